// Round 3
// baseline (138.945 us; speedup 1.0000x reference)
//
#include <hip/hip_runtime.h>
#include <hip/hip_bf16.h>

// Problem constants (from reference)
#define DIM   128
#define KNEG  20

// Numerically stable log(sigmoid(x)) = -softplus(-x)
__device__ __forceinline__ float log_sigmoid(float x) {
    float ax = fabsf(x);
    float t = log1pf(__expf(-ax));
    return (x >= 0.0f) ? -t : (x - t);
}

__global__ __launch_bounds__(256) void skipgram_loss_kernel(
    const float* __restrict__ u_emb,   // [VOCAB, 128] float32
    const float* __restrict__ v_emb,   // [VOCAB, 128] float32
    const int* __restrict__ u_pos,     // [B] int32
    const int* __restrict__ v_pos,     // [B] int32
    const int* __restrict__ v_neg,     // [B, 20] int32
    float* __restrict__ acc,           // [1] float accumulator (pre-zeroed)
    int B_total)
{
    const int lane  = threadIdx.x & 63;
    const int wib   = threadIdx.x >> 6;                 // wave in block (0..3)
    const int wave  = blockIdx.x * 4 + wib;
    const int nwave = gridDim.x * 4;
    const int col   = lane * 2;                         // 2 floats per lane -> 512B/row

    float local = 0.0f;

    for (int b = wave; b < B_total; b += nwave) {
        const int ui = u_pos[b];
        const int vi = v_pos[b];

        // u row: 2 floats per lane (float2 = 8B; rows are 512B-aligned)
        const float2 uu = *(const float2*)(u_emb + (size_t)ui * DIM + col);

        // positive v row -> dot partial
        const float2 vv = *(const float2*)(v_emb + (size_t)vi * DIM + col);
        float p = uu.x * vv.x + uu.y * vv.y;

        // negative indices (wave-uniform within a wave; issue all up front for ILP)
        int nidx[KNEG];
        #pragma unroll
        for (int k = 0; k < KNEG; ++k) nidx[k] = v_neg[b * KNEG + k];

        // Sum the 20 neg rows elementwise first (sum over k commutes with the
        // dot because the reference sums neg_score over k BEFORE log_sigmoid).
        float ns0 = 0.0f, ns1 = 0.0f;
        #pragma unroll
        for (int k = 0; k < KNEG; ++k) {
            const float2 nv = *(const float2*)(v_emb + (size_t)nidx[k] * DIM + col);
            ns0 += nv.x;
            ns1 += nv.y;
        }
        float nd = uu.x * ns0 + uu.y * ns1;

        // Wave-level sum reduce (64 lanes) of both dots
        #pragma unroll
        for (int off = 32; off > 0; off >>= 1) {
            p  += __shfl_xor(p,  off, 64);
            nd += __shfl_xor(nd, off, 64);
        }

        if (lane == 0) {
            local += log_sigmoid(p) + log_sigmoid(-nd);
        }
    }

    // Block reduce (4 waves) -> one atomic per block
    __shared__ float sbuf[4];
    if (lane == 0) sbuf[wib] = local;
    __syncthreads();
    if (threadIdx.x == 0) {
        float s = sbuf[0] + sbuf[1] + sbuf[2] + sbuf[3];
        atomicAdd(acc, s);
    }
}

__global__ void finalize_kernel(const float* __restrict__ acc,
                                const int* __restrict__ batch_size,
                                float* __restrict__ out)
{
    out[0] = -acc[0] / (float)batch_size[0];   // output is float32
}

extern "C" void kernel_launch(void* const* d_in, const int* in_sizes, int n_in,
                              void* d_out, int out_size, void* d_ws, size_t ws_size,
                              hipStream_t stream) {
    const float* u_emb = (const float*)d_in[0];
    const float* v_emb = (const float*)d_in[1];
    const int* u_pos = (const int*)d_in[2];
    const int* v_pos = (const int*)d_in[3];
    const int* v_neg = (const int*)d_in[4];
    const int* bsz   = (const int*)d_in[5];

    const int B_total = in_sizes[2];   // number of positive pairs (16384)

    float* acc = (float*)d_ws;
    hipMemsetAsync(acc, 0, sizeof(float), stream);

    // 1024 blocks x 4 waves = 4096 waves; each wave handles B/4096 = 4 elements
    const int blocks = 1024;
    skipgram_loss_kernel<<<blocks, 256, 0, stream>>>(
        u_emb, v_emb, u_pos, v_pos, v_neg, acc, B_total);

    finalize_kernel<<<1, 1, 0, stream>>>(acc, bsz, (float*)d_out);
}

// Round 4
// 135.450 us; speedup vs baseline: 1.0258x; 1.0258x over previous
//
#include <hip/hip_runtime.h>
#include <hip/hip_bf16.h>

// Problem constants (from reference)
#define DIM   128
#define KNEG  20

// Numerically stable log(sigmoid(x)) = -softplus(-x)
__device__ __forceinline__ float log_sigmoid(float x) {
    float ax = fabsf(x);
    float t = log1pf(__expf(-ax));
    return (x >= 0.0f) ? -t : (x - t);
}

// One wave (64 lanes) per batch element.
// Row layout: 128 floats = 512 B. 32 lanes x float4 cover one row, so each
// 64-lane gather instruction fetches TWO rows (row r = 2*i + half).
__global__ __launch_bounds__(256) void skipgram_loss_kernel(
    const float* __restrict__ u_emb,   // [VOCAB, 128] float32
    const float* __restrict__ v_emb,   // [VOCAB, 128] float32
    const int* __restrict__ u_pos,     // [B] int32
    const int* __restrict__ v_pos,     // [B] int32
    const int* __restrict__ v_neg,     // [B, 20] int32
    float* __restrict__ partials,      // [gridDim.x] per-block partial sums
    int B_total)
{
    const int lane = threadIdx.x & 63;
    const int wib  = threadIdx.x >> 6;          // wave in block (0..3)
    const int b    = blockIdx.x * 4 + wib;      // batch element for this wave
    const int half = lane >> 5;                 // 0 or 1: which row of the pair
    const int l32  = lane & 31;
    const int col  = l32 * 4;                   // float4 column within a row

    float p = 0.0f;                             // positive-dot partial
    float nd = 0.0f;                            // neg-sum-dot partial

    if (b < B_total) {
        // Gather all 22 indices with ONE load instruction (lanes 0..21 active):
        //   lane 0     -> v_pos[b]
        //   lanes 1-20 -> v_neg[b*20 + lane-1]
        //   lane 21    -> u_pos[b]
        int myidx = 0;
        if (lane == 0)           myidx = v_pos[b];
        else if (lane <= KNEG)   myidx = v_neg[b * KNEG + lane - 1];
        else if (lane == 21)     myidx = u_pos[b];

        const int ui = __shfl(myidx, 21, 64);
        const float4 U = *(const float4*)(u_emb + (size_t)ui * DIM + col);

        float4 ns = make_float4(0.f, 0.f, 0.f, 0.f);   // elementwise sum of my neg rows
        #pragma unroll
        for (int i = 0; i < 11; ++i) {
            const int r  = 2 * i + half;        // 0..21; r=0 is v_pos, 1..20 are negs
            const int rr = (r <= KNEG) ? r : KNEG;          // clamp for safe load
            const int idx = __shfl(myidx, rr, 64);
            const float4 row = *(const float4*)(v_emb + (size_t)idx * DIM + col);
            if (r == 0) {
                p = U.x * row.x + U.y * row.y + U.z * row.z + U.w * row.w;
            } else if (r <= KNEG) {
                ns.x += row.x; ns.y += row.y; ns.z += row.z; ns.w += row.w;
            }
        }
        nd = U.x * ns.x + U.y * ns.y + U.z * ns.z + U.w * ns.w;
    }

    // Wave-level sum reduce (64 lanes) of both dots
    #pragma unroll
    for (int off = 32; off > 0; off >>= 1) {
        p  += __shfl_xor(p,  off, 64);
        nd += __shfl_xor(nd, off, 64);
    }

    float local = 0.0f;
    if (lane == 0 && b < B_total) {
        local = log_sigmoid(p) + log_sigmoid(-nd);
    }

    // Block reduce (4 waves) -> plain store of this block's partial (no atomics,
    // no init needed even though d_ws is poisoned).
    __shared__ float sbuf[4];
    if (lane == 0) sbuf[wib] = local;
    __syncthreads();
    if (threadIdx.x == 0) {
        partials[blockIdx.x] = sbuf[0] + sbuf[1] + sbuf[2] + sbuf[3];
    }
}

__global__ __launch_bounds__(256) void finalize_kernel(
    const float* __restrict__ partials, int n,
    const int* __restrict__ batch_size,
    float* __restrict__ out)
{
    const int lane = threadIdx.x & 63;
    const int wib  = threadIdx.x >> 6;

    float s = 0.0f;
    for (int i = threadIdx.x; i < n; i += 256) s += partials[i];

    #pragma unroll
    for (int off = 32; off > 0; off >>= 1) s += __shfl_xor(s, off, 64);

    __shared__ float sbuf[4];
    if (lane == 0) sbuf[wib] = s;
    __syncthreads();
    if (threadIdx.x == 0) {
        float total = sbuf[0] + sbuf[1] + sbuf[2] + sbuf[3];
        out[0] = -total / (float)batch_size[0];   // output is float32
    }
}

extern "C" void kernel_launch(void* const* d_in, const int* in_sizes, int n_in,
                              void* d_out, int out_size, void* d_ws, size_t ws_size,
                              hipStream_t stream) {
    const float* u_emb = (const float*)d_in[0];
    const float* v_emb = (const float*)d_in[1];
    const int* u_pos = (const int*)d_in[2];
    const int* v_pos = (const int*)d_in[3];
    const int* v_neg = (const int*)d_in[4];
    const int* bsz   = (const int*)d_in[5];

    const int B_total = in_sizes[2];           // 16384
    const int blocks  = (B_total + 3) / 4;     // one wave per element, 4 waves/block

    float* partials = (float*)d_ws;

    skipgram_loss_kernel<<<blocks, 256, 0, stream>>>(
        u_emb, v_emb, u_pos, v_pos, v_neg, partials, B_total);

    finalize_kernel<<<1, 256, 0, stream>>>(partials, blocks, bsz, (float*)d_out);
}

// Round 5
// 134.723 us; speedup vs baseline: 1.0313x; 1.0054x over previous
//
#include <hip/hip_runtime.h>
#include <hip/hip_bf16.h>

// Problem constants (from reference)
#define DIM   128
#define KNEG  20

// Numerically stable log(sigmoid(x)) = -softplus(-x)
__device__ __forceinline__ float log_sigmoid(float x) {
    float ax = fabsf(x);
    float t = log1pf(__expf(-ax));
    return (x >= 0.0f) ? -t : (x - t);
}

// One batch element per 32-lane HALF-wave (2 elements per wave).
// A 128-float row = 512 B = 32 lanes x float4, so each half-wave covers a
// full row per load instruction; the two halves fetch rows of two different
// elements in the same instruction — zero wasted lanes, zero wasted rows.
// Per wave: 1 index load + 2 U loads' worth folded into 23 total VMEM ops
// for 2 elements (11.5 instr/elem vs 13 before, and no discarded row).
__global__ __launch_bounds__(256) void skipgram_loss_kernel(
    const float* __restrict__ u_emb,   // [VOCAB, 128] float32
    const float* __restrict__ v_emb,   // [VOCAB, 128] float32
    const int* __restrict__ u_pos,     // [B] int32
    const int* __restrict__ v_pos,     // [B] int32
    const int* __restrict__ v_neg,     // [B, 20] int32
    float* __restrict__ partials,      // [gridDim.x] per-block partial sums
    int B_total)
{
    const int lane  = threadIdx.x & 63;
    const int wib   = threadIdx.x >> 6;         // wave in block (0..3)
    const int half  = lane >> 5;                // which half-wave (0/1)
    const int l32   = lane & 31;
    const int col   = l32 * 4;                  // float4 column within a row
    const int b     = (blockIdx.x * 4 + wib) * 2 + half;  // element for this half
    const int hbase = half << 5;

    float p = 0.0f, nd = 0.0f;
    const bool valid = (b < B_total);

    // Gather the 22 indices of this half's element with one load instruction:
    //   l32 0     -> v_pos[b]
    //   l32 1..20 -> v_neg[b*20 + l32-1]
    //   l32 21    -> u_pos[b]
    int myidx = 0;
    if (valid) {
        if (l32 == 0)            myidx = v_pos[b];
        else if (l32 <= KNEG)    myidx = v_neg[b * KNEG + l32 - 1];
        else if (l32 == 21)      myidx = u_pos[b];
    }

    if (valid) {
        const int ui = __shfl(myidx, hbase + 21, 64);
        const float4 U = *(const float4*)(u_emb + (size_t)ui * DIM + col);

        float4 ns = make_float4(0.f, 0.f, 0.f, 0.f);
        #pragma unroll
        for (int r = 0; r <= KNEG; ++r) {       // r=0: positive, r=1..20: negatives
            const int idx = __shfl(myidx, hbase + r, 64);
            const float4 row = *(const float4*)(v_emb + (size_t)idx * DIM + col);
            if (r == 0) {
                p = U.x * row.x + U.y * row.y + U.z * row.z + U.w * row.w;
            } else {
                ns.x += row.x; ns.y += row.y; ns.z += row.z; ns.w += row.w;
            }
        }
        nd = U.x * ns.x + U.y * ns.y + U.z * ns.z + U.w * ns.w;
    }

    // Reduce within each 32-lane half (offsets < 32 stay inside the half)
    #pragma unroll
    for (int off = 16; off > 0; off >>= 1) {
        p  += __shfl_xor(p,  off, 64);
        nd += __shfl_xor(nd, off, 64);
    }

    float local = 0.0f;
    if (l32 == 0 && valid) {
        local = log_sigmoid(p) + log_sigmoid(-nd);
    }
    // Combine the two halves: lane0 += lane32's value
    local += __shfl_xor(local, 32, 64);

    // Block reduce (4 waves) -> plain store of this block's partial
    __shared__ float sbuf[4];
    if (lane == 0) sbuf[wib] = local;
    __syncthreads();
    if (threadIdx.x == 0) {
        partials[blockIdx.x] = sbuf[0] + sbuf[1] + sbuf[2] + sbuf[3];
    }
}

__global__ __launch_bounds__(256) void finalize_kernel(
    const float* __restrict__ partials, int n,
    const int* __restrict__ batch_size,
    float* __restrict__ out)
{
    const int lane = threadIdx.x & 63;
    const int wib  = threadIdx.x >> 6;

    float s = 0.0f;
    for (int i = threadIdx.x; i < n; i += 256) s += partials[i];

    #pragma unroll
    for (int off = 32; off > 0; off >>= 1) s += __shfl_xor(s, off, 64);

    __shared__ float sbuf[4];
    if (lane == 0) sbuf[wib] = s;
    __syncthreads();
    if (threadIdx.x == 0) {
        float total = sbuf[0] + sbuf[1] + sbuf[2] + sbuf[3];
        out[0] = -total / (float)batch_size[0];   // output is float32
    }
}

extern "C" void kernel_launch(void* const* d_in, const int* in_sizes, int n_in,
                              void* d_out, int out_size, void* d_ws, size_t ws_size,
                              hipStream_t stream) {
    const float* u_emb = (const float*)d_in[0];
    const float* v_emb = (const float*)d_in[1];
    const int* u_pos = (const int*)d_in[2];
    const int* v_pos = (const int*)d_in[3];
    const int* v_neg = (const int*)d_in[4];
    const int* bsz   = (const int*)d_in[5];

    const int B_total = in_sizes[2];           // 16384
    // 2 elements per wave, 4 waves per block -> 8 elements per block.
    const int blocks = (B_total + 7) / 8;      // 2048 blocks = 8192 waves = 32/CU, single pass

    float* partials = (float*)d_ws;

    skipgram_loss_kernel<<<blocks, 256, 0, stream>>>(
        u_emb, v_emb, u_pos, v_pos, v_neg, partials, B_total);

    finalize_kernel<<<1, 256, 0, stream>>>(partials, blocks, bsz, (float*)d_out);
}